// Round 14
// baseline (166.181 us; speedup 1.0000x reference)
//
#include <hip/hip_runtime.h>
#include <hip/hip_bf16.h>

// Sparse conv for MI355X (gfx950), fused output-stationary design:
//   kA : rank-blocks (LDS nibble counters -> sparse slot table [row][27][4] u16)
//        + wt-blocks (kern f32 -> transposed bf16 wt[k][c][i], built once)
//        + cast-blocks (f32 -> bf16 feature table fb)
//   kF : 512-thread blocks (8 waves x 16 rows). W staged in 7-offset chunks
//        (63KB LDS); inner k-loop barrier-free; feature gathers DEPTH-1
//        SOFTWARE-PIPELINED in register double-buffers (issue k+1 in body k,
//        consume one full body later -- no barrier in between to drain vmcnt).
//   k4 : overflow fixup (~500 pairs) recomputes feat.W, atomicAdd.
// Fallback to a pure-atomic kernel for exotic shapes / tiny ws.

typedef __bf16 bf16x8 __attribute__((ext_vector_type(8)));
typedef float f32x4 __attribute__((ext_vector_type(4)));

#define KOFF 27
#define SLOTK 4                 // slots per (row,k) cell
#define NSLOT (KOFF * SLOTK)    // 108 entries per row
#define OVFCAP 8192             // overflow list capacity (E[ovf] ~ 505)
#define WPAD 72                 // LDS pad for W tile
#define WTILE (64 * WPAD)       // 4608 elems per offset
#define KCH 7                   // offsets per LDS chunk (7*4608*2B = 63KB)
#define ROWCHUNK 8192           // rows per rank-block chunk
#define NIBW (ROWCHUNK / 8)     // 4 KB LDS nibble counters

// ---- kA: chunked rank-builder + W transpose/cast + feature cast ----
__global__ __launch_bounds__(256) void kA_rank_cast(
    const float* __restrict__ feat, const float* __restrict__ kern,
    const int* __restrict__ nout, __bf16* __restrict__ fb,
    __bf16* __restrict__ wt, unsigned short* __restrict__ slots,
    int2* __restrict__ ovf, int* __restrict__ ovfcnt, int Lpairs, int nElems,
    int nchunk, int rankBlocks, int wtBlocks) {
  __shared__ unsigned int nib[NIBW];
  if ((int)blockIdx.x < rankBlocks) {
    const int k = blockIdx.x / nchunk;
    const int chunk = blockIdx.x % nchunk;
    const int lo = chunk * ROWCHUNK;
    const int tid = threadIdx.x;
    for (int i = tid; i < NIBW; i += 256) nib[i] = 0u;
    __syncthreads();
    const int* nk = nout + k * Lpairs;
    for (int base = 0; base < Lpairs; base += 2048) {
      int l[8], row[8];
#pragma unroll
      for (int j = 0; j < 8; ++j) {
        l[j] = base + j * 256 + tid;
        row[j] = (l[j] < Lpairs) ? nk[l[j]] : -1;
      }
#pragma unroll
      for (int j = 0; j < 8; ++j) {
        int rr = row[j] - lo;
        if (rr >= 0 && rr < ROWCHUNK) {
          unsigned int sh = ((unsigned)rr & 7u) * 4u;
          unsigned int old = atomicAdd(&nib[rr >> 3], 1u << sh);
          int rank = (old >> sh) & 15;
          if (rank < SLOTK) {
            slots[(size_t)row[j] * NSLOT + k * SLOTK + rank] =
                (unsigned short)l[j];
          } else {
            int idx = atomicAdd(ovfcnt, 1);
            if (idx < OVFCAP) ovf[idx] = make_int2(row[j], k * Lpairs + l[j]);
          }
        }
      }
    }
  } else if ((int)blockIdx.x < rankBlocks + wtBlocks) {
    // W transpose/cast: wt[k][c*64+i] = (bf16)kern[k*4096 + i*64 + c]
    int kc = (blockIdx.x - rankBlocks) * 256 + threadIdx.x;
    if (kc < KOFF * 64) {
      int k = kc >> 6, c = kc & 63;
      const float* src = kern + k * 4096 + c;
      __bf16* dst = wt + (size_t)kc * 64;
#pragma unroll
      for (int i0 = 0; i0 < 64; i0 += 8) {
        bf16x8 v;
#pragma unroll
        for (int q = 0; q < 8; ++q) v[q] = (__bf16)src[(i0 + q) * 64];
        *(bf16x8*)(dst + i0) = v;
      }
    }
  } else {
    int i = ((blockIdx.x - rankBlocks - wtBlocks) * 256 + threadIdx.x) * 8;
    if (i < nElems) {
      f32x4 a = *(const f32x4*)(feat + i);
      f32x4 b = *(const f32x4*)(feat + i + 4);
      bf16x8 v;
#pragma unroll
      for (int j = 0; j < 4; ++j) {
        v[j] = (__bf16)a[j];
        v[j + 4] = (__bf16)b[j];
      }
      *(bf16x8*)(fb + i) = v;
    }
  }
}

// ---- kF: fused output-stationary GEMM, chunked W staging, pipelined gather ----
// Wave handles 16 rows. Lane (g=lane>>4, r=lane&15):
//   B operand per k: summed cell features of row (rowbase+r)
//   A operand: W[k]^T fragments from LDS chunk (staged 7 offsets at a time)
//   D: col=r -> row, row=g*4+reg (+t*16) -> channel; persistent across k.
__global__ __launch_bounds__(512, 4) void kF_fused(
    const __bf16* __restrict__ fb, const __bf16* __restrict__ wt,
    const int* __restrict__ nin, const unsigned short* __restrict__ slots,
    float* __restrict__ out, int Lpairs, int Nrows) {
  __shared__ __bf16 ldsW[KCH * WTILE];  // 64512 B
  const int tid = threadIdx.x;
  const int wv = tid >> 6, lane = tid & 63;
  const int r = lane & 15, g = lane >> 4;
  int row = blockIdx.x * 128 + wv * 16 + r;
  if (row >= Nrows) row = Nrows - 1;  // duplicate rows write identical values
  const unsigned short* srow = slots + (size_t)row * NSLOT;

  // staging coords: thread copies W row c = tid>>3, elems [si, si+8)
  const int sc = tid >> 3;
  const int si = (tid & 7) * 8;

  // Index prologue: slot entries for k=0,1,2; nin rows for k=0,1.
  uint2 sv0 = *(const uint2*)(srow);
  uint2 sv1 = *(const uint2*)(srow + SLOTK);
  uint2 sv2 = *(const uint2*)(srow + 2 * SLOTK);
  int e0[4] = {(int)(sv0.x & 0xFFFF), (int)(sv0.x >> 16),
               (int)(sv0.y & 0xFFFF), (int)(sv0.y >> 16)};
  int e1[4] = {(int)(sv1.x & 0xFFFF), (int)(sv1.x >> 16),
               (int)(sv1.y & 0xFFFF), (int)(sv1.y >> 16)};
  int enN[4] = {(int)(sv2.x & 0xFFFF), (int)(sv2.x >> 16),
                (int)(sv2.y & 0xFFFF), (int)(sv2.y >> 16)};
  int irowNxt[4];
  int gA[4], gB[4];
#pragma unroll
  for (int j = 0; j < 4; ++j) gA[j] = (e0[j] != 0xFFFF) ? nin[e0[j]] : -1;
  const int* nin1 = nin + Lpairs;
#pragma unroll
  for (int j = 0; j < 4; ++j) irowNxt[j] = (e1[j] != 0xFFFF) ? nin1[e1[j]] : -1;

  f32x4 acc[4] = {f32x4{0.f, 0.f, 0.f, 0.f}, f32x4{0.f, 0.f, 0.f, 0.f},
                  f32x4{0.f, 0.f, 0.f, 0.f}, f32x4{0.f, 0.f, 0.f, 0.f}};

  // Gather double-buffers (registers). Issue gather(0) into A now; its latency
  // overlaps the first chunk's W staging below.
  bf16x8 faA[4], fcA[4], faB[4], fcB[4];
#pragma unroll
  for (int j = 0; j < 4; ++j) {
    if (gA[j] >= 0) {
      const __bf16* ap = fb + (size_t)gA[j] * 64 + g * 8;
      faA[j] = *(const bf16x8*)(ap);
      fcA[j] = *(const bf16x8*)(ap + 32);
    }
  }

  // Per-k body. Consumes buffer C (gathers issued one body ago); issues
  // gather(k+1) into buffer N. Barrier-free.
  auto body = [&](int k, int kk, bf16x8(&faC)[4], bf16x8(&fcC)[4], int(&gC)[4],
                  bf16x8(&faN)[4], bf16x8(&fcN)[4], int(&gN)[4]) {
    // (1) issue gather(k+1) into N (full-body latency window before consume)
#pragma unroll
    for (int j = 0; j < 4; ++j) gN[j] = (k + 1 < KOFF) ? irowNxt[j] : -1;
#pragma unroll
    for (int j = 0; j < 4; ++j) {
      if (gN[j] >= 0) {
        const __bf16* ap = fb + (size_t)gN[j] * 64 + g * 8;
        faN[j] = *(const bf16x8*)(ap);
        fcN[j] = *(const bf16x8*)(ap + 32);
      }
    }
    // (2) nin rows for k+2
    const int* nin2 = nin + (size_t)(k + 2) * Lpairs;
    int irowN2[4];
#pragma unroll
    for (int j = 0; j < 4; ++j)
      irowN2[j] = (k + 2 < KOFF && enN[j] != 0xFFFF) ? nin2[enN[j]] : -1;
    // (3) slot entries for k+3
    uint2 sv3 = make_uint2(0xFFFFFFFFu, 0xFFFFFFFFu);
    if (k + 3 < KOFF) sv3 = *(const uint2*)(srow + (k + 3) * SLOTK);
    // (4) presum(k) from C in f32 (linearity: sum before GEMM)
    float s0[8] = {0.f, 0.f, 0.f, 0.f, 0.f, 0.f, 0.f, 0.f};
    float s1[8] = {0.f, 0.f, 0.f, 0.f, 0.f, 0.f, 0.f, 0.f};
#pragma unroll
    for (int j = 0; j < 4; ++j) {
      if (gC[j] >= 0) {
#pragma unroll
        for (int q = 0; q < 8; ++q) {
          s0[q] += (float)faC[j][q];
          s1[q] += (float)fcC[j][q];
        }
      }
    }
    bf16x8 b0, b1;
#pragma unroll
    for (int q = 0; q < 8; ++q) {
      b0[q] = (__bf16)s0[q];
      b1[q] = (__bf16)s1[q];
    }
    // (5) W fragments from LDS chunk + 8 MFMAs into persistent acc
    bf16x8 w0f[4], w1f[4];
#pragma unroll
    for (int t = 0; t < 4; ++t) {
      w0f[t] = *(const bf16x8*)&ldsW[kk * WTILE + (t * 16 + r) * WPAD + g * 8];
      w1f[t] = *(const bf16x8*)&ldsW[kk * WTILE + (t * 16 + r) * WPAD + g * 8 + 32];
    }
#pragma unroll
    for (int t = 0; t < 4; ++t) {
      acc[t] = __builtin_amdgcn_mfma_f32_16x16x32_bf16(w0f[t], b0, acc[t], 0, 0, 0);
      acc[t] = __builtin_amdgcn_mfma_f32_16x16x32_bf16(w1f[t], b1, acc[t], 0, 0, 0);
    }
    // (6) rotate index pipeline
#pragma unroll
    for (int j = 0; j < 4; ++j) irowNxt[j] = irowN2[j];
    enN[0] = (int)(sv3.x & 0xFFFF);
    enN[1] = (int)(sv3.x >> 16);
    enN[2] = (int)(sv3.y & 0xFFFF);
    enN[3] = (int)(sv3.y >> 16);
  };

  // 4 chunks of 7/7/7/6 offsets; 2 barriers per chunk; inner loop barrier-free.
  // Fully unrolled so k-parity (A/B buffer naming) is static (rule #20).
#pragma unroll
  for (int c = 0; c < 4; ++c) {
    const int kbase = c * KCH;
    const int kcnt = (c < 3) ? KCH : (KOFF - 3 * KCH);  // 7,7,7,6
    if (c) __syncthreads();  // all waves done reading previous chunk's W
#pragma unroll
    for (int kk = 0; kk < KCH; ++kk) {
      if (kk < kcnt) {
        bf16x8 w = *(const bf16x8*)(wt + (size_t)(kbase + kk) * 4096 + sc * 64 + si);
        *(bf16x8*)&ldsW[kk * WTILE + sc * WPAD + si] = w;
      }
    }
    __syncthreads();  // staged W visible
#pragma unroll
    for (int kk = 0; kk < KCH; ++kk) {
      if (kk < kcnt) {
        const int k = kbase + kk;
        if ((k & 1) == 0)
          body(k, kk, faA, fcA, gA, faB, fcB, gB);
        else
          body(k, kk, faB, fcB, gB, faA, fcA, gA);
      }
    }
  }

  // Epilogue: lane (g,r) holds channels t*16+g*4+{0..3} of row.
  float* op = out + (size_t)row * 64;
#pragma unroll
  for (int t = 0; t < 4; ++t) *(f32x4*)(op + t * 16 + g * 4) = acc[t];
}

// ---- k4: overflow fixup (~500 pairs): recompute feat.W (bf16), atomicAdd ----
__global__ __launch_bounds__(256) void k4_fixup(
    const __bf16* __restrict__ fb, const __bf16* __restrict__ wt,
    const int* __restrict__ nin, const int2* __restrict__ ovf,
    const int* __restrict__ ovfcnt, float* __restrict__ out, int Lpairs) {
  int gid = blockIdx.x * 256 + threadIdx.x;
  int i = gid >> 6, c = gid & 63;
  int n = *ovfcnt;
  if (n > OVFCAP) n = OVFCAP;
  if (i >= n) return;
  int row = ovf[i].x, pid = ovf[i].y;
  int k = pid / Lpairs;
  int irow = nin[pid];
  const __bf16* wk = wt + ((size_t)k * 64 + c) * 64;  // wt[k][c][*]
  const __bf16* f = fb + (size_t)irow * 64;
  float s = 0.f;
#pragma unroll 8
  for (int q = 0; q < 64; ++q) s += (float)f[q] * (float)wk[q];
  atomicAdd(&out[(size_t)row * 64 + c], s);
}

// ---- Fallback: atomic kernel (exotic shapes / tiny ws) ----
__global__ __launch_bounds__(256) void spconv_atomic_kernel(
    const float* __restrict__ feat, const float* __restrict__ kern,
    const int* __restrict__ nin, const int* __restrict__ nout,
    float* __restrict__ out, int Lpairs, int blocksPerK) {
  __shared__ __bf16 ldsBT[64 * WPAD];
  const int bk = blockIdx.x / blocksPerK;
  const int chunk = blockIdx.x % blocksPerK;
  const float* kb = kern + bk * 4096;
  for (int idx = threadIdx.x; idx < 4096; idx += 256) {
    int i = idx >> 6, c = idx & 63;
    ldsBT[c * WPAD + i] = (__bf16)kb[idx];
  }
  __syncthreads();
  const int lane = threadIdx.x & 63;
  const int wave = threadIdx.x >> 6;
  const int r = lane & 15, g = lane >> 4;
  bf16x8 bfrag[2][4];
#pragma unroll
  for (int s = 0; s < 2; ++s)
#pragma unroll
    for (int t = 0; t < 4; ++t)
      bfrag[s][t] = *(const bf16x8*)&ldsBT[(t * 16 + r) * WPAD + g * 8 + s * 32];
  const int* ninK = nin + bk * Lpairs;
  const int* noutK = nout + bk * Lpairs;
  const int base0 = chunk * 512 + wave * 128;
  for (int it = 0; it < 8; ++it) {
    const int base = base0 + it * 16;
    if (base >= Lpairs) break;
    const int arow = ninK[base + r];
    const float* ap = feat + (size_t)arow * 64 + g * 8;
    f32x4 f0 = *(const f32x4*)(ap);
    f32x4 f1 = *(const f32x4*)(ap + 4);
    f32x4 f2 = *(const f32x4*)(ap + 32);
    f32x4 f3 = *(const f32x4*)(ap + 36);
    bf16x8 a0, a1;
#pragma unroll
    for (int j = 0; j < 4; ++j) {
      a0[j] = (__bf16)f0[j];
      a0[j + 4] = (__bf16)f1[j];
      a1[j] = (__bf16)f2[j];
      a1[j + 4] = (__bf16)f3[j];
    }
    f32x4 acc[4] = {f32x4{0.f, 0.f, 0.f, 0.f}, f32x4{0.f, 0.f, 0.f, 0.f},
                    f32x4{0.f, 0.f, 0.f, 0.f}, f32x4{0.f, 0.f, 0.f, 0.f}};
#pragma unroll
    for (int t = 0; t < 4; ++t) {
      acc[t] = __builtin_amdgcn_mfma_f32_16x16x32_bf16(a0, bfrag[0][t], acc[t], 0, 0, 0);
      acc[t] = __builtin_amdgcn_mfma_f32_16x16x32_bf16(a1, bfrag[1][t], acc[t], 0, 0, 0);
    }
    int orow[4];
#pragma unroll
    for (int reg = 0; reg < 4; ++reg) orow[reg] = noutK[base + g * 4 + reg];
#pragma unroll
    for (int t = 0; t < 4; ++t)
#pragma unroll
      for (int reg = 0; reg < 4; ++reg)
        atomicAdd(out + (size_t)orow[reg] * 64 + t * 16 + r, acc[t][reg]);
  }
}

extern "C" void kernel_launch(void* const* d_in, const int* in_sizes, int n_in,
                              void* d_out, int out_size, void* d_ws, size_t ws_size,
                              hipStream_t stream) {
  const float* feat = (const float*)d_in[0];
  const float* kern = (const float*)d_in[1];
  const int* nin = (const int*)d_in[2];
  const int* nout = (const int*)d_in[3];
  float* out = (float*)d_out;

  const int total = in_sizes[2];        // 27*L pairs
  const int Lpairs = total / KOFF;      // 50000
  const int Nrows = out_size / 64;      // 100000
  const int nElems = Nrows * 64;

  // ws layout: slots (u16, 0xFF-init) | ovf | ovfcnt | wt (bf16 W^T) | fb
  const size_t slotsBytes = (size_t)Nrows * NSLOT * 2;
  const size_t ovfOff = (slotsBytes + 255) & ~(size_t)255;
  const size_t cntOff = (ovfOff + (size_t)OVFCAP * 8 + 255) & ~(size_t)255;
  const size_t wtOff = (cntOff + 256 + 255) & ~(size_t)255;
  const size_t fbOff = (wtOff + (size_t)KOFF * 4096 * 2 + 255) & ~(size_t)255;
  const size_t needed = fbOff + (size_t)nElems * 2;

  const bool shapeOK = (Lpairs <= 65535) && (Lpairs % 16 == 0) &&
                       (total % KOFF == 0) && (out_size % 64 == 0);

  if (shapeOK && ws_size >= needed) {
    unsigned short* slots = (unsigned short*)d_ws;
    int2* ovf = (int2*)((char*)d_ws + ovfOff);
    int* ovfcnt = (int*)((char*)d_ws + cntOff);
    __bf16* wt = (__bf16*)((char*)d_ws + wtOff);
    __bf16* fb = (__bf16*)((char*)d_ws + fbOff);

    hipMemsetAsync(slots, 0xFF, slotsBytes, stream);
    hipMemsetAsync(ovfcnt, 0, 4, stream);

    const int nchunk = (Nrows + ROWCHUNK - 1) / ROWCHUNK;
    const int rankBlocks = KOFF * nchunk;
    const int wtBlocks = (KOFF * 64 + 255) / 256;  // 7
    const int castBlocks = (nElems / 8 + 255) / 256;
    kA_rank_cast<<<rankBlocks + wtBlocks + castBlocks, 256, 0, stream>>>(
        feat, kern, nout, fb, wt, slots, ovf, ovfcnt, Lpairs, nElems, nchunk,
        rankBlocks, wtBlocks);
    kF_fused<<<(Nrows + 127) / 128, 512, 0, stream>>>(fb, wt, nin, slots, out,
                                                      Lpairs, Nrows);
    k4_fixup<<<OVFCAP * 64 / 256, 256, 0, stream>>>(fb, wt, nin, ovf, ovfcnt,
                                                    out, Lpairs);
  } else {
    const int blocksPerK = (Lpairs + 511) / 512;
    hipMemsetAsync(d_out, 0, (size_t)out_size * sizeof(float), stream);
    spconv_atomic_kernel<<<KOFF * blocksPerK, 256, 0, stream>>>(
        feat, kern, nin, nout, out, Lpairs, blocksPerK);
  }
}

// Round 15
// 149.896 us; speedup vs baseline: 1.1086x; 1.1086x over previous
//
#include <hip/hip_runtime.h>
#include <hip/hip_bf16.h>

// Sparse conv for MI355X (gfx950), fused output-stationary design (r10 base,
// dual row-group waves for 2x memory-level parallelism):
//   kA : rank-blocks (LDS nibble counters -> sparse slot table [row][27][4] u16)
//        + wt-blocks (kern f32 -> transposed bf16 wt[k][c][i], built once)
//        + cast-blocks (f32 -> bf16 feature table fb)
//   kF : wave owns 32 output rows (2 MFMA row-groups). Per k: issue 16
//        independent gathers (2 cells x 8), presum both, read W frags from LDS
//        ONCE, 16 MFMAs. acc[2][64ch][16rows] persistent in regs. W staged
//        per-k in double-buffered LDS (r10's proven schedule).
//   k4 : overflow fixup (~500 pairs) recomputes feat.W, atomicAdd.
// Fallback to a pure-atomic kernel for exotic shapes / tiny ws.

typedef __bf16 bf16x8 __attribute__((ext_vector_type(8)));
typedef float f32x4 __attribute__((ext_vector_type(4)));

#define KOFF 27
#define SLOTK 4                 // slots per (row,k) cell
#define NSLOT (KOFF * SLOTK)    // 108 entries per row
#define OVFCAP 8192             // overflow list capacity (E[ovf] ~ 505)
#define WPAD 72                 // LDS pad for W tile
#define ROWCHUNK 8192           // rows per rank-block chunk
#define NIBW (ROWCHUNK / 8)     // 4 KB LDS nibble counters

// ---- kA: chunked rank-builder + W transpose/cast + feature cast ----
__global__ __launch_bounds__(256) void kA_rank_cast(
    const float* __restrict__ feat, const float* __restrict__ kern,
    const int* __restrict__ nout, __bf16* __restrict__ fb,
    __bf16* __restrict__ wt, unsigned short* __restrict__ slots,
    int2* __restrict__ ovf, int* __restrict__ ovfcnt, int Lpairs, int nElems,
    int nchunk, int rankBlocks, int wtBlocks) {
  __shared__ unsigned int nib[NIBW];
  if ((int)blockIdx.x < rankBlocks) {
    const int k = blockIdx.x / nchunk;
    const int chunk = blockIdx.x % nchunk;
    const int lo = chunk * ROWCHUNK;
    const int tid = threadIdx.x;
    for (int i = tid; i < NIBW; i += 256) nib[i] = 0u;
    __syncthreads();
    const int* nk = nout + k * Lpairs;
    for (int base = 0; base < Lpairs; base += 2048) {
      int l[8], row[8];
#pragma unroll
      for (int j = 0; j < 8; ++j) {
        l[j] = base + j * 256 + tid;
        row[j] = (l[j] < Lpairs) ? nk[l[j]] : -1;
      }
#pragma unroll
      for (int j = 0; j < 8; ++j) {
        int rr = row[j] - lo;
        if (rr >= 0 && rr < ROWCHUNK) {
          unsigned int sh = ((unsigned)rr & 7u) * 4u;
          unsigned int old = atomicAdd(&nib[rr >> 3], 1u << sh);
          int rank = (old >> sh) & 15;
          if (rank < SLOTK) {
            slots[(size_t)row[j] * NSLOT + k * SLOTK + rank] =
                (unsigned short)l[j];
          } else {
            int idx = atomicAdd(ovfcnt, 1);
            if (idx < OVFCAP) ovf[idx] = make_int2(row[j], k * Lpairs + l[j]);
          }
        }
      }
    }
  } else if ((int)blockIdx.x < rankBlocks + wtBlocks) {
    // W transpose/cast: wt[k][c*64+i] = (bf16)kern[k*4096 + i*64 + c]
    int kc = (blockIdx.x - rankBlocks) * 256 + threadIdx.x;
    if (kc < KOFF * 64) {
      int k = kc >> 6, c = kc & 63;
      const float* src = kern + k * 4096 + c;
      __bf16* dst = wt + (size_t)kc * 64;
#pragma unroll
      for (int i0 = 0; i0 < 64; i0 += 8) {
        bf16x8 v;
#pragma unroll
        for (int q = 0; q < 8; ++q) v[q] = (__bf16)src[(i0 + q) * 64];
        *(bf16x8*)(dst + i0) = v;
      }
    }
  } else {
    int i = ((blockIdx.x - rankBlocks - wtBlocks) * 256 + threadIdx.x) * 8;
    if (i < nElems) {
      f32x4 a = *(const f32x4*)(feat + i);
      f32x4 b = *(const f32x4*)(feat + i + 4);
      bf16x8 v;
#pragma unroll
      for (int j = 0; j < 4; ++j) {
        v[j] = (__bf16)a[j];
        v[j + 4] = (__bf16)b[j];
      }
      *(bf16x8*)(fb + i) = v;
    }
  }
}

// ---- kF: fused output-stationary GEMM, dual row-group waves ----
// Wave handles 32 rows: group0 = rowbase+r, group1 = rowbase+16+r.
//   B operands per k: summed cell features of each group's row
//   A operand: W[k]^T fragments from LDS (read once, used by both groups)
//   D: col=r -> row, row=g*4+reg (+t*16) -> channel; persistent across k.
__global__ __launch_bounds__(256) void kF_fused(
    const __bf16* __restrict__ fb, const __bf16* __restrict__ wt,
    const int* __restrict__ nin, const unsigned short* __restrict__ slots,
    float* __restrict__ out, int Lpairs, int Nrows) {
  __shared__ __bf16 ldsW[2][64 * WPAD];
  const int tid = threadIdx.x;
  const int wv = tid >> 6, lane = tid & 63;
  const int r = lane & 15, g = lane >> 4;
  int row0 = blockIdx.x * 128 + wv * 32 + r;
  int row1 = row0 + 16;
  if (row0 >= Nrows) row0 = Nrows - 1;  // duplicates write identical values
  if (row1 >= Nrows) row1 = Nrows - 1;
  const unsigned short* srow0 = slots + (size_t)row0 * NSLOT;
  const unsigned short* srow1 = slots + (size_t)row1 * NSLOT;

  // staging coords: thread copies W row c = tid>>2, elems [si, si+16)
  const int sc = tid >> 2;
  const int si = (tid & 3) * 16;

  // stage W[0]: pure vector copy (2 x 16B load, 2 x ds_write_b128)
  {
    const __bf16* wp = wt + sc * 64 + si;
    bf16x8 wa = *(const bf16x8*)(wp);
    bf16x8 wb = *(const bf16x8*)(wp + 8);
    *(bf16x8*)&ldsW[0][sc * WPAD + si] = wa;
    *(bf16x8*)&ldsW[0][sc * WPAD + si + 8] = wb;
  }

  // Index prologue per group: slot entries for k=0,1; nin rows for k=0.
  uint2 s0a = *(const uint2*)(srow0);
  uint2 s0b = *(const uint2*)(srow0 + SLOTK);
  uint2 s1a = *(const uint2*)(srow1);
  uint2 s1b = *(const uint2*)(srow1 + SLOTK);
  int en0[4] = {(int)(s0b.x & 0xFFFF), (int)(s0b.x >> 16),
                (int)(s0b.y & 0xFFFF), (int)(s0b.y >> 16)};
  int en1[4] = {(int)(s1b.x & 0xFFFF), (int)(s1b.x >> 16),
                (int)(s1b.y & 0xFFFF), (int)(s1b.y >> 16)};
  int e0[4] = {(int)(s0a.x & 0xFFFF), (int)(s0a.x >> 16),
               (int)(s0a.y & 0xFFFF), (int)(s0a.y >> 16)};
  int e1[4] = {(int)(s1a.x & 0xFFFF), (int)(s1a.x >> 16),
               (int)(s1a.y & 0xFFFF), (int)(s1a.y >> 16)};
  int irow0[4], irow1[4], irown0[4], irown1[4];
#pragma unroll
  for (int j = 0; j < 4; ++j) {
    irow0[j] = (e0[j] != 0xFFFF) ? nin[e0[j]] : -1;
    irow1[j] = (e1[j] != 0xFFFF) ? nin[e1[j]] : -1;
  }

  f32x4 acc0[4] = {f32x4{0.f, 0.f, 0.f, 0.f}, f32x4{0.f, 0.f, 0.f, 0.f},
                   f32x4{0.f, 0.f, 0.f, 0.f}, f32x4{0.f, 0.f, 0.f, 0.f}};
  f32x4 acc1[4] = {f32x4{0.f, 0.f, 0.f, 0.f}, f32x4{0.f, 0.f, 0.f, 0.f},
                   f32x4{0.f, 0.f, 0.f, 0.f}, f32x4{0.f, 0.f, 0.f, 0.f}};
  __syncthreads();

  for (int k = 0; k < KOFF; ++k) {
    const int kb = k & 1;
    // (1) W-load(k+1) into regs, earliest
    bf16x8 wa, wb;
    if (k + 1 < KOFF) {
      const __bf16* wp = wt + (size_t)(k + 1) * 4096 + sc * 64 + si;
      wa = *(const bf16x8*)(wp);
      wb = *(const bf16x8*)(wp + 8);
    }
    // (2) issue ALL 16 gathers for k (2 groups x 4 slots x 2 halves)
    bf16x8 fa0[4], fc0[4], fa1[4], fc1[4];
#pragma unroll
    for (int j = 0; j < 4; ++j) {
      if (irow0[j] >= 0) {
        const __bf16* ap = fb + (size_t)irow0[j] * 64 + g * 8;
        fa0[j] = *(const bf16x8*)(ap);
        fc0[j] = *(const bf16x8*)(ap + 32);
      }
    }
#pragma unroll
    for (int j = 0; j < 4; ++j) {
      if (irow1[j] >= 0) {
        const __bf16* ap = fb + (size_t)irow1[j] * 64 + g * 8;
        fa1[j] = *(const bf16x8*)(ap);
        fc1[j] = *(const bf16x8*)(ap + 32);
      }
    }
    // (3) nin rows for k+1 (both groups)
    const int* nin1 = nin + (size_t)(k + 1) * Lpairs;
#pragma unroll
    for (int j = 0; j < 4; ++j) {
      irown0[j] = (k + 1 < KOFF && en0[j] != 0xFFFF) ? nin1[en0[j]] : -1;
      irown1[j] = (k + 1 < KOFF && en1[j] != 0xFFFF) ? nin1[en1[j]] : -1;
    }
    // (4) slot entries for k+2 (both groups)
    uint2 sv20 = make_uint2(0xFFFFFFFFu, 0xFFFFFFFFu);
    uint2 sv21 = make_uint2(0xFFFFFFFFu, 0xFFFFFFFFu);
    if (k + 2 < KOFF) {
      sv20 = *(const uint2*)(srow0 + (k + 2) * SLOTK);
      sv21 = *(const uint2*)(srow1 + (k + 2) * SLOTK);
    }
    // (5) presum both groups (group0's loads are oldest -> ready first)
    float p00[8] = {0.f, 0.f, 0.f, 0.f, 0.f, 0.f, 0.f, 0.f};
    float p01[8] = {0.f, 0.f, 0.f, 0.f, 0.f, 0.f, 0.f, 0.f};
#pragma unroll
    for (int j = 0; j < 4; ++j) {
      if (irow0[j] >= 0) {
#pragma unroll
        for (int q = 0; q < 8; ++q) {
          p00[q] += (float)fa0[j][q];
          p01[q] += (float)fc0[j][q];
        }
      }
    }
    float p10[8] = {0.f, 0.f, 0.f, 0.f, 0.f, 0.f, 0.f, 0.f};
    float p11[8] = {0.f, 0.f, 0.f, 0.f, 0.f, 0.f, 0.f, 0.f};
#pragma unroll
    for (int j = 0; j < 4; ++j) {
      if (irow1[j] >= 0) {
#pragma unroll
        for (int q = 0; q < 8; ++q) {
          p10[q] += (float)fa1[j][q];
          p11[q] += (float)fc1[j][q];
        }
      }
    }
    bf16x8 b00, b01, b10, b11;
#pragma unroll
    for (int q = 0; q < 8; ++q) {
      b00[q] = (__bf16)p00[q];
      b01[q] = (__bf16)p01[q];
      b10[q] = (__bf16)p10[q];
      b11[q] = (__bf16)p11[q];
    }
    // (6) W fragments from LDS (ONCE) + 16 MFMAs into persistent accs
    bf16x8 w0f[4], w1f[4];
#pragma unroll
    for (int t = 0; t < 4; ++t) {
      w0f[t] = *(const bf16x8*)&ldsW[kb][(t * 16 + r) * WPAD + g * 8];
      w1f[t] = *(const bf16x8*)&ldsW[kb][(t * 16 + r) * WPAD + g * 8 + 32];
    }
#pragma unroll
    for (int t = 0; t < 4; ++t) {
      acc0[t] = __builtin_amdgcn_mfma_f32_16x16x32_bf16(w0f[t], b00, acc0[t], 0, 0, 0);
      acc0[t] = __builtin_amdgcn_mfma_f32_16x16x32_bf16(w1f[t], b01, acc0[t], 0, 0, 0);
      acc1[t] = __builtin_amdgcn_mfma_f32_16x16x32_bf16(w0f[t], b10, acc1[t], 0, 0, 0);
      acc1[t] = __builtin_amdgcn_mfma_f32_16x16x32_bf16(w1f[t], b11, acc1[t], 0, 0, 0);
    }
    // (7) ds_write W(k+1) + one barrier per k
    if (k + 1 < KOFF) {
      *(bf16x8*)&ldsW[kb ^ 1][sc * WPAD + si] = wa;
      *(bf16x8*)&ldsW[kb ^ 1][sc * WPAD + si + 8] = wb;
      __syncthreads();
    }
    // (8) rotate index pipelines
#pragma unroll
    for (int j = 0; j < 4; ++j) {
      irow0[j] = irown0[j];
      irow1[j] = irown1[j];
    }
    en0[0] = (int)(sv20.x & 0xFFFF);
    en0[1] = (int)(sv20.x >> 16);
    en0[2] = (int)(sv20.y & 0xFFFF);
    en0[3] = (int)(sv20.y >> 16);
    en1[0] = (int)(sv21.x & 0xFFFF);
    en1[1] = (int)(sv21.x >> 16);
    en1[2] = (int)(sv21.y & 0xFFFF);
    en1[3] = (int)(sv21.y >> 16);
  }

  // Epilogue: lane (g,r) holds channels t*16+g*4+{0..3} of each row.
  float* op0 = out + (size_t)row0 * 64;
  float* op1 = out + (size_t)row1 * 64;
#pragma unroll
  for (int t = 0; t < 4; ++t) *(f32x4*)(op0 + t * 16 + g * 4) = acc0[t];
#pragma unroll
  for (int t = 0; t < 4; ++t) *(f32x4*)(op1 + t * 16 + g * 4) = acc1[t];
}

// ---- k4: overflow fixup (~500 pairs): recompute feat.W (bf16), atomicAdd ----
__global__ __launch_bounds__(256) void k4_fixup(
    const __bf16* __restrict__ fb, const __bf16* __restrict__ wt,
    const int* __restrict__ nin, const int2* __restrict__ ovf,
    const int* __restrict__ ovfcnt, float* __restrict__ out, int Lpairs) {
  int gid = blockIdx.x * 256 + threadIdx.x;
  int i = gid >> 6, c = gid & 63;
  int n = *ovfcnt;
  if (n > OVFCAP) n = OVFCAP;
  if (i >= n) return;
  int row = ovf[i].x, pid = ovf[i].y;
  int k = pid / Lpairs;
  int irow = nin[pid];
  const __bf16* wk = wt + ((size_t)k * 64 + c) * 64;  // wt[k][c][*]
  const __bf16* f = fb + (size_t)irow * 64;
  float s = 0.f;
#pragma unroll 8
  for (int q = 0; q < 64; ++q) s += (float)f[q] * (float)wk[q];
  atomicAdd(&out[(size_t)row * 64 + c], s);
}

// ---- Fallback: atomic kernel (exotic shapes / tiny ws) ----
__global__ __launch_bounds__(256) void spconv_atomic_kernel(
    const float* __restrict__ feat, const float* __restrict__ kern,
    const int* __restrict__ nin, const int* __restrict__ nout,
    float* __restrict__ out, int Lpairs, int blocksPerK) {
  __shared__ __bf16 ldsBT[64 * WPAD];
  const int bk = blockIdx.x / blocksPerK;
  const int chunk = blockIdx.x % blocksPerK;
  const float* kb = kern + bk * 4096;
  for (int idx = threadIdx.x; idx < 4096; idx += 256) {
    int i = idx >> 6, c = idx & 63;
    ldsBT[c * WPAD + i] = (__bf16)kb[idx];
  }
  __syncthreads();
  const int lane = threadIdx.x & 63;
  const int wave = threadIdx.x >> 6;
  const int r = lane & 15, g = lane >> 4;
  bf16x8 bfrag[2][4];
#pragma unroll
  for (int s = 0; s < 2; ++s)
#pragma unroll
    for (int t = 0; t < 4; ++t)
      bfrag[s][t] = *(const bf16x8*)&ldsBT[(t * 16 + r) * WPAD + g * 8 + s * 32];
  const int* ninK = nin + bk * Lpairs;
  const int* noutK = nout + bk * Lpairs;
  const int base0 = chunk * 512 + wave * 128;
  for (int it = 0; it < 8; ++it) {
    const int base = base0 + it * 16;
    if (base >= Lpairs) break;
    const int arow = ninK[base + r];
    const float* ap = feat + (size_t)arow * 64 + g * 8;
    f32x4 f0 = *(const f32x4*)(ap);
    f32x4 f1 = *(const f32x4*)(ap + 4);
    f32x4 f2 = *(const f32x4*)(ap + 32);
    f32x4 f3 = *(const f32x4*)(ap + 36);
    bf16x8 a0, a1;
#pragma unroll
    for (int j = 0; j < 4; ++j) {
      a0[j] = (__bf16)f0[j];
      a0[j + 4] = (__bf16)f1[j];
      a1[j] = (__bf16)f2[j];
      a1[j + 4] = (__bf16)f3[j];
    }
    f32x4 acc[4] = {f32x4{0.f, 0.f, 0.f, 0.f}, f32x4{0.f, 0.f, 0.f, 0.f},
                    f32x4{0.f, 0.f, 0.f, 0.f}, f32x4{0.f, 0.f, 0.f, 0.f}};
#pragma unroll
    for (int t = 0; t < 4; ++t) {
      acc[t] = __builtin_amdgcn_mfma_f32_16x16x32_bf16(a0, bfrag[0][t], acc[t], 0, 0, 0);
      acc[t] = __builtin_amdgcn_mfma_f32_16x16x32_bf16(a1, bfrag[1][t], acc[t], 0, 0, 0);
    }
    int orow[4];
#pragma unroll
    for (int reg = 0; reg < 4; ++reg) orow[reg] = noutK[base + g * 4 + reg];
#pragma unroll
    for (int t = 0; t < 4; ++t)
#pragma unroll
      for (int reg = 0; reg < 4; ++reg)
        atomicAdd(out + (size_t)orow[reg] * 64 + t * 16 + r, acc[t][reg]);
  }
}

extern "C" void kernel_launch(void* const* d_in, const int* in_sizes, int n_in,
                              void* d_out, int out_size, void* d_ws, size_t ws_size,
                              hipStream_t stream) {
  const float* feat = (const float*)d_in[0];
  const float* kern = (const float*)d_in[1];
  const int* nin = (const int*)d_in[2];
  const int* nout = (const int*)d_in[3];
  float* out = (float*)d_out;

  const int total = in_sizes[2];        // 27*L pairs
  const int Lpairs = total / KOFF;      // 50000
  const int Nrows = out_size / 64;      // 100000
  const int nElems = Nrows * 64;

  // ws layout: slots (u16, 0xFF-init) | ovf | ovfcnt | wt (bf16 W^T) | fb
  const size_t slotsBytes = (size_t)Nrows * NSLOT * 2;
  const size_t ovfOff = (slotsBytes + 255) & ~(size_t)255;
  const size_t cntOff = (ovfOff + (size_t)OVFCAP * 8 + 255) & ~(size_t)255;
  const size_t wtOff = (cntOff + 256 + 255) & ~(size_t)255;
  const size_t fbOff = (wtOff + (size_t)KOFF * 4096 * 2 + 255) & ~(size_t)255;
  const size_t needed = fbOff + (size_t)nElems * 2;

  const bool shapeOK = (Lpairs <= 65535) && (Lpairs % 16 == 0) &&
                       (total % KOFF == 0) && (out_size % 64 == 0);

  if (shapeOK && ws_size >= needed) {
    unsigned short* slots = (unsigned short*)d_ws;
    int2* ovf = (int2*)((char*)d_ws + ovfOff);
    int* ovfcnt = (int*)((char*)d_ws + cntOff);
    __bf16* wt = (__bf16*)((char*)d_ws + wtOff);
    __bf16* fb = (__bf16*)((char*)d_ws + fbOff);

    hipMemsetAsync(slots, 0xFF, slotsBytes, stream);
    hipMemsetAsync(ovfcnt, 0, 4, stream);

    const int nchunk = (Nrows + ROWCHUNK - 1) / ROWCHUNK;
    const int rankBlocks = KOFF * nchunk;
    const int wtBlocks = (KOFF * 64 + 255) / 256;  // 7
    const int castBlocks = (nElems / 8 + 255) / 256;
    kA_rank_cast<<<rankBlocks + wtBlocks + castBlocks, 256, 0, stream>>>(
        feat, kern, nout, fb, wt, slots, ovf, ovfcnt, Lpairs, nElems, nchunk,
        rankBlocks, wtBlocks);
    kF_fused<<<(Nrows + 127) / 128, 256, 0, stream>>>(fb, wt, nin, slots, out,
                                                      Lpairs, Nrows);
    k4_fixup<<<OVFCAP * 64 / 256, 256, 0, stream>>>(fb, wt, nin, ovf, ovfcnt,
                                                    out, Lpairs);
  } else {
    const int blocksPerK = (Lpairs + 511) / 512;
    hipMemsetAsync(d_out, 0, (size_t)out_size * sizeof(float), stream);
    spconv_atomic_kernel<<<KOFF * blocksPerK, 256, 0, stream>>>(
        feat, kern, nin, nout, out, Lpairs, blocksPerK);
  }
}